// Round 4
// baseline (188.528 us; speedup 1.0000x reference)
//
#include <hip/hip_runtime.h>
#include <math.h>

// GCN 2-layer, N=100K, E=3.2M, feat 1->16->2, log_softmax.
//
// R5 lessons (rocprof): (1) random-order 8B writes amplify ~2.8x at HBM ->
// sort tile in LDS, stream out coalesced. (2) per-edge binary search = 9
// dependent ds_reads -> once-per-block LDS run-offset table. (3) halve random
// gathers: xd = dinv*x, gd = dinv*gamma; factor dinv[dst] into epilogue.
//
// R6 lesson: 66KB-LDS coop monolith -> 12 waves/CU, VALUBusy 2.4%, +90us coop
// overhead. Latency-bound => occupancy is king.
//
// R7 lesson (rocprof): random global atomicAdd = memory-side RMW, ~32B HBM
// traffic per 4B atomic (~103MB, +115us). NEVER random global atomics here.
//
// R8 lesson: EPB 7936->4096 + int4 edge loads fixed scatter (175 -> <42us;
// fell out of top-5). Top-5 now all harness 256MiB workspace fills (43us) ->
// our 4 kernels sum to ~143us, ~35us each.
//
// R9 (this round): agg grid imbalance. nb=391 blocks of 1024 thr on 256 CUs
// with 2-block/CU capacity = 1.53 avg -> half the CUs idle half the pass.
// CHUNK 256->128, BLOCK_A 1024->512: nb=782 blocks, 4 blocks/CU capacity
// (LDS ~29KB, TABCAP halves), 3.05 avg -> worst-case imbalance 1.3x. Scans
// go pair-wise (2 elems/thread) since nb,nblk > 512; rowOffT prologue reads
// become uint2.

static constexpr int BLOCK_S   = 512;    // scatter threads
static constexpr int EPB       = 4096;   // edges per scatter tile (32 KB LDS)
static constexpr int VITERS    = EPB / (BLOCK_S * 4);  // 2 (int4 groups)
static constexpr int CHUNK     = 128;    // nodes per bucket (pow2)
static constexpr int LOG_CHUNK = 7;
static constexpr int BLOCK_A   = 512;    // aggregation threads
static constexpr int MAXNB     = 1024;   // max buckets (N <= 131072)
static constexpr int MAXBLK    = 1024;   // max scatter tiles (E <= 4.19M)
static constexpr int TABCAP    = 5120;   // run-table entries (bucket size bound)

// ======================= shfl-based scan =======================
// 512-thread inclusive scan: 2 barriers.
__device__ __forceinline__ unsigned int incl_scan512(unsigned int v,
                                                     unsigned int* wsum, int t) {
    unsigned int x = v;
#pragma unroll
    for (int off = 1; off < 64; off <<= 1) {
        unsigned int y = __shfl_up(x, off, 64);
        if ((t & 63) >= off) x += y;
    }
    if ((t & 63) == 63) wsum[t >> 6] = x;
    __syncthreads();
    if (t < 8) {
        unsigned int s = wsum[t];
#pragma unroll
        for (int off = 1; off < 8; off <<= 1) {
            unsigned int y = __shfl_up(s, off, 64);
            if (t >= off) s += y;
        }
        wsum[t] = s;
    }
    __syncthreads();
    return x + ((t >= 64) ? wsum[(t >> 6) - 1] : 0u);
}

__device__ __forceinline__ int run_adj_fallback(const unsigned int* cumx,
                                                const int* radj,
                                                unsigned int i, int nblk) {
    int lo = 0, hi = nblk - 1;
    while (lo < hi) {
        int mid = (lo + hi + 1) >> 1;
        if (cumx[mid] <= i) lo = mid; else hi = mid - 1;
    }
    return radj[lo];
}

// ======================= scatter: LDS sort + coalesced write-out =======================

__global__ __launch_bounds__(BLOCK_S) void scatter_kernel(
    const int* __restrict__ src, const int* __restrict__ dst,
    const float* __restrict__ w,
    unsigned int* __restrict__ rowOffT,        // [(nb+1)][nblk] transposed
    unsigned long long* __restrict__ payload,  // [nblk*EPB]
    int E, int nb, int nblk) {
    __shared__ unsigned long long pbuf[EPB];   // 32768 B staging
    __shared__ unsigned int hist[MAXNB];       // 4096 B (reused as cursor)
    __shared__ unsigned int wsum[8];
    const int blk  = blockIdx.x;
    const int base = blk * EPB;
    const int nE   = min(EPB, E - base);       // multiple of 4 (E, EPB mult 4)
    const int t    = threadIdx.x;

    hist[t]           = 0u;
    hist[t + BLOCK_S] = 0u;
    __syncthreads();

    int4 dc[VITERS];                           // static indexing -> VGPRs
#pragma unroll
    for (int i = 0; i < VITERS; ++i) {
        const int k = 4 * t + i * 4 * BLOCK_S;
        int4 d4 = make_int4(0, 0, 0, 0);
        if (k < nE) {
            d4 = *reinterpret_cast<const int4*>(&dst[base + k]);
            atomicAdd(&hist[(unsigned int)d4.x >> LOG_CHUNK], 1u);
            atomicAdd(&hist[(unsigned int)d4.y >> LOG_CHUNK], 1u);
            atomicAdd(&hist[(unsigned int)d4.z >> LOG_CHUNK], 1u);
            atomicAdd(&hist[(unsigned int)d4.w >> LOG_CHUNK], 1u);
        }
        dc[i] = d4;
    }
    __syncthreads();

    // pair-wise scan: thread t owns buckets 2t, 2t+1 (nb <= 1024)
    const unsigned int v0 = hist[2 * t], v1 = hist[2 * t + 1];
    const unsigned int pr = v0 + v1;
    const unsigned int inclp = incl_scan512(pr, wsum, t);
    const unsigned int ex0 = inclp - pr;
    const unsigned int ex1 = ex0 + v0;
    if (2 * t < nb)     rowOffT[(size_t)(2 * t) * nblk + blk]     = ex0;
    if (2 * t + 1 < nb) rowOffT[(size_t)(2 * t + 1) * nblk + blk] = ex1;
    if (t == 0)         rowOffT[(size_t)nb * nblk + blk] = (unsigned int)nE;
    hist[2 * t]     = ex0;                      // -> cursor
    hist[2 * t + 1] = ex1;
    __syncthreads();

#pragma unroll
    for (int i = 0; i < VITERS; ++i) {
        const int k = 4 * t + i * 4 * BLOCK_S;
        if (k < nE) {
            const int4   d4 = dc[i];
            const int4   s4 = *reinterpret_cast<const int4*>(&src[base + k]);
            const float4 w4 = *reinterpret_cast<const float4*>(&w[base + k]);
#define SCAT_ONE(dd, ss, ww)                                                  \
            {                                                                 \
                const unsigned int slot =                                     \
                    atomicAdd(&hist[(unsigned int)(dd) >> LOG_CHUNK], 1u);    \
                pbuf[slot] =                                                  \
                    ((unsigned long long)__float_as_uint(ww) << 32) |         \
                    ((unsigned int)(ss) << LOG_CHUNK) |                       \
                    (unsigned int)((dd) & (CHUNK - 1));                       \
            }
            SCAT_ONE(d4.x, s4.x, w4.x)
            SCAT_ONE(d4.y, s4.y, w4.y)
            SCAT_ONE(d4.z, s4.z, w4.z)
            SCAT_ONE(d4.w, s4.w, w4.w)
#undef SCAT_ONE
        }
    }
    __syncthreads();
    // coalesced, in-order global write-out, 16B per lane (nE multiple of 4)
    for (int k2 = t; k2 < (nE >> 1); k2 += BLOCK_S) {
        ulonglong2 v = *reinterpret_cast<const ulonglong2*>(&pbuf[2 * k2]);
        *reinterpret_cast<ulonglong2*>(&payload[(size_t)base + 2 * k2]) = v;
    }
}

// ======================= aggregation kernels =======================
// Prologue: uint2 coalesced rowOffT reads + pair-wise shfl scan (2 barriers)
// + run-offset table. Inner loop: 4-wide MLP unroll over the
// table->payload->gather->LDS-atomic chain.

#define AGG_PROLOGUE                                                          \
    const int b = blockIdx.x, t = threadIdx.x;                                \
    const int e0 = 2 * t, e1 = 2 * t + 1;                                     \
    unsigned int s00 = 0, s01 = 0, len0 = 0, len1 = 0;                        \
    if (e0 < nblk) {                                                          \
        const uint2 r0 =                                                      \
            *reinterpret_cast<const uint2*>(&rowOffT[(size_t)b * nblk + e0]); \
        const uint2 r1 =                                                      \
            *reinterpret_cast<const uint2*>(&rowOffT[(size_t)(b + 1) * nblk + e0]); \
        s00 = r0.x; s01 = r0.y;                                               \
        len0 = r1.x - r0.x;                                                   \
        len1 = (e1 < nblk) ? (r1.y - r0.y) : 0u;                              \
    }                                                                         \
    const unsigned int pr_    = len0 + len1;                                  \
    const unsigned int inclp_ = incl_scan512(pr_, wsum, t);                   \
    const unsigned int ex0_   = inclp_ - pr_;                                 \
    const unsigned int ex1_   = ex0_ + len0;                                  \
    if (e0 < nblk) { cumx[e0] = ex0_; radj[e0] = (int)s00 - (int)ex0_ + e0 * EPB; } \
    if (e1 < nblk) { cumx[e1] = ex1_; radj[e1] = (int)s01 - (int)ex1_ + e1 * EPB; } \
    if (t == ((nblk - 1) >> 1)) totsh = inclp_;                               \
    if (t < CHUNK) acc[t] = 0.0f;                                             \
    __syncthreads();                                                          \
    const unsigned int total = totsh;                                         \
    for (int r = e0; r <= e1 && r < nblk; ++r) {                              \
        const unsigned int beg = cumx[r];                                     \
        const unsigned int end = (r == nblk - 1) ? total : cumx[r + 1];       \
        const unsigned int lim = min(end, (unsigned int)TABCAP);              \
        const int a_ = radj[r];                                               \
        for (unsigned int i = beg; i < lim; ++i) table[i] = a_;               \
    }                                                                         \
    __syncthreads();

#define TAB(i) (((i) < (unsigned int)TABCAP) ? table[i]                       \
                                             : run_adj_fallback(cumx, radj, (i), nblk))

// ---- pass A: degree -> dinv, xd (no gather in the chain) ----
__global__ __launch_bounds__(BLOCK_A) void deg_dinv_kernel(
    const unsigned long long* __restrict__ payload,
    const unsigned int* __restrict__ rowOffT,
    const float* __restrict__ x,
    float* __restrict__ dinv, float* __restrict__ xd,
    int N, int nb, int nblk) {
    __shared__ unsigned int cumx[MAXBLK];
    __shared__ int          radj[MAXBLK];
    __shared__ float        acc[CHUNK];
    __shared__ int          table[TABCAP];
    __shared__ unsigned int wsum[8];
    __shared__ unsigned int totsh;
    AGG_PROLOGUE
    unsigned int i = t;
    for (; i + 3u * BLOCK_A < total; i += 4u * BLOCK_A) {
        const unsigned int i0 = i, i1 = i + BLOCK_A, i2 = i + 2u * BLOCK_A,
                           i3 = i + 3u * BLOCK_A;
        const int a0 = TAB(i0), a1 = TAB(i1), a2 = TAB(i2), a3 = TAB(i3);
        const unsigned long long p0 = payload[(unsigned int)(a0 + (int)i0)];
        const unsigned long long p1 = payload[(unsigned int)(a1 + (int)i1)];
        const unsigned long long p2 = payload[(unsigned int)(a2 + (int)i2)];
        const unsigned long long p3 = payload[(unsigned int)(a3 + (int)i3)];
        atomicAdd(&acc[(unsigned int)p0 & (CHUNK - 1)],
                  __uint_as_float((unsigned int)(p0 >> 32)));
        atomicAdd(&acc[(unsigned int)p1 & (CHUNK - 1)],
                  __uint_as_float((unsigned int)(p1 >> 32)));
        atomicAdd(&acc[(unsigned int)p2 & (CHUNK - 1)],
                  __uint_as_float((unsigned int)(p2 >> 32)));
        atomicAdd(&acc[(unsigned int)p3 & (CHUNK - 1)],
                  __uint_as_float((unsigned int)(p3 >> 32)));
    }
    for (; i < total; i += BLOCK_A) {
        const int adj = TAB(i);
        const unsigned long long p = payload[(unsigned int)(adj + (int)i)];
        atomicAdd(&acc[(unsigned int)p & (CHUNK - 1)],
                  __uint_as_float((unsigned int)(p >> 32)));
    }
    __syncthreads();
    const int n = b * CHUNK + t;
    if (t < CHUNK && n < N) {
        const float d = acc[t] + 1.0f;           // self-loop fill 1.0
        const float r = (d > 0.0f) ? rsqrtf(d) : 0.0f;
        dinv[n] = r;
        xd[n]   = r * x[n];
    }
}

// ---- pass B: s -> relu-MLP -> gd ----
__global__ __launch_bounds__(BLOCK_A) void s_gamma_kernel(
    const unsigned long long* __restrict__ payload,
    const unsigned int* __restrict__ rowOffT,
    const float* __restrict__ dinv,
    const float* __restrict__ xd,
    const float* __restrict__ W1,    // [16]
    const float* __restrict__ b1,    // [16]
    const float* __restrict__ W2,    // [16][2]
    float* __restrict__ gd, int N, int nb, int nblk) {
    __shared__ unsigned int cumx[MAXBLK];
    __shared__ int          radj[MAXBLK];
    __shared__ float        acc[CHUNK];
    __shared__ int          table[TABCAP];
    __shared__ unsigned int wsum[8];
    __shared__ unsigned int totsh;
    AGG_PROLOGUE
    unsigned int i = t;
    for (; i + 3u * BLOCK_A < total; i += 4u * BLOCK_A) {
        const unsigned int i0 = i, i1 = i + BLOCK_A, i2 = i + 2u * BLOCK_A,
                           i3 = i + 3u * BLOCK_A;
        const int a0 = TAB(i0), a1 = TAB(i1), a2 = TAB(i2), a3 = TAB(i3);
        const unsigned long long p0 = payload[(unsigned int)(a0 + (int)i0)];
        const unsigned long long p1 = payload[(unsigned int)(a1 + (int)i1)];
        const unsigned long long p2 = payload[(unsigned int)(a2 + (int)i2)];
        const unsigned long long p3 = payload[(unsigned int)(a3 + (int)i3)];
        const float f0 = xd[(int)(((unsigned int)p0) >> LOG_CHUNK)];
        const float f1 = xd[(int)(((unsigned int)p1) >> LOG_CHUNK)];
        const float f2 = xd[(int)(((unsigned int)p2) >> LOG_CHUNK)];
        const float f3 = xd[(int)(((unsigned int)p3) >> LOG_CHUNK)];
        atomicAdd(&acc[(unsigned int)p0 & (CHUNK - 1)],
                  __uint_as_float((unsigned int)(p0 >> 32)) * f0);
        atomicAdd(&acc[(unsigned int)p1 & (CHUNK - 1)],
                  __uint_as_float((unsigned int)(p1 >> 32)) * f1);
        atomicAdd(&acc[(unsigned int)p2 & (CHUNK - 1)],
                  __uint_as_float((unsigned int)(p2 >> 32)) * f2);
        atomicAdd(&acc[(unsigned int)p3 & (CHUNK - 1)],
                  __uint_as_float((unsigned int)(p3 >> 32)) * f3);
    }
    for (; i < total; i += BLOCK_A) {
        const int adj = TAB(i);
        const unsigned long long p = payload[(unsigned int)(adj + (int)i)];
        atomicAdd(&acc[(unsigned int)p & (CHUNK - 1)],
                  __uint_as_float((unsigned int)(p >> 32)) *
                      xd[(int)(((unsigned int)p) >> LOG_CHUNK)]);
    }
    __syncthreads();
    const int n = b * CHUNK + t;
    if (t < CHUNK && n < N) {
        const float dv = dinv[n];
        const float sv = dv * (acc[t] + xd[n]);   // + self-loop dv*dv*x[n]
        float g = 0.0f;
#pragma unroll
        for (int f = 0; f < 16; ++f) {
            const float h = fmaxf(sv * W1[f] + b1[f], 0.0f);   // relu(layer1)
            g += h * (W2[2 * f + 1] - W2[2 * f + 0]);          // gamma = g1-g0
        }
        gd[n] = dv * g;                           // pre-scaled for layer 2
    }
}

// ---- pass C: d -> log_softmax out ----
__global__ __launch_bounds__(BLOCK_A) void d_out_kernel(
    const unsigned long long* __restrict__ payload,
    const unsigned int* __restrict__ rowOffT,
    const float* __restrict__ dinv,
    const float* __restrict__ gd,
    const float* __restrict__ b2,    // [2]
    float* __restrict__ out, int N, int nb, int nblk) {
    __shared__ unsigned int cumx[MAXBLK];
    __shared__ int          radj[MAXBLK];
    __shared__ float        acc[CHUNK];
    __shared__ int          table[TABCAP];
    __shared__ unsigned int wsum[8];
    __shared__ unsigned int totsh;
    AGG_PROLOGUE
    unsigned int i = t;
    for (; i + 3u * BLOCK_A < total; i += 4u * BLOCK_A) {
        const unsigned int i0 = i, i1 = i + BLOCK_A, i2 = i + 2u * BLOCK_A,
                           i3 = i + 3u * BLOCK_A;
        const int a0 = TAB(i0), a1 = TAB(i1), a2 = TAB(i2), a3 = TAB(i3);
        const unsigned long long p0 = payload[(unsigned int)(a0 + (int)i0)];
        const unsigned long long p1 = payload[(unsigned int)(a1 + (int)i1)];
        const unsigned long long p2 = payload[(unsigned int)(a2 + (int)i2)];
        const unsigned long long p3 = payload[(unsigned int)(a3 + (int)i3)];
        const float f0 = gd[(int)(((unsigned int)p0) >> LOG_CHUNK)];
        const float f1 = gd[(int)(((unsigned int)p1) >> LOG_CHUNK)];
        const float f2 = gd[(int)(((unsigned int)p2) >> LOG_CHUNK)];
        const float f3 = gd[(int)(((unsigned int)p3) >> LOG_CHUNK)];
        atomicAdd(&acc[(unsigned int)p0 & (CHUNK - 1)],
                  __uint_as_float((unsigned int)(p0 >> 32)) * f0);
        atomicAdd(&acc[(unsigned int)p1 & (CHUNK - 1)],
                  __uint_as_float((unsigned int)(p1 >> 32)) * f1);
        atomicAdd(&acc[(unsigned int)p2 & (CHUNK - 1)],
                  __uint_as_float((unsigned int)(p2 >> 32)) * f2);
        atomicAdd(&acc[(unsigned int)p3 & (CHUNK - 1)],
                  __uint_as_float((unsigned int)(p3 >> 32)) * f3);
    }
    for (; i < total; i += BLOCK_A) {
        const int adj = TAB(i);
        const unsigned long long p = payload[(unsigned int)(adj + (int)i)];
        atomicAdd(&acc[(unsigned int)p & (CHUNK - 1)],
                  __uint_as_float((unsigned int)(p >> 32)) *
                      gd[(int)(((unsigned int)p) >> LOG_CHUNK)]);
    }
    __syncthreads();
    const int n = b * CHUNK + t;
    if (t < CHUNK && n < N) {
        const float dv = dinv[n];
        const float d = dv * (acc[t] + gd[n]) + (b2[1] - b2[0]);
        // 2-class log_softmax from d = a1 - a0 (stable)
        const float lse = fmaxf(d, 0.0f) + log1pf(expf(-fabsf(d)));
        out[2 * n + 0] = -lse;
        out[2 * n + 1] = d - lse;
    }
}

// ======================= fallback: R3 global-atomic path =======================

static constexpr int BLOCK = 256;

__global__ void zero_kernel(float* __restrict__ a, float* __restrict__ b, int n2) {
    int i = blockIdx.x * blockDim.x + threadIdx.x;
    if (i < n2) { a[i] = 0.0f; b[i] = 0.0f; }
}
__global__ void deg_kernel(const int* __restrict__ dst, const float* __restrict__ w,
                           float* __restrict__ deg, int E) {
    int e = blockIdx.x * blockDim.x + threadIdx.x;
    if (e < E) atomicAdd(&deg[dst[e]], w[e]);
}
__global__ void dinv_kernel(float* __restrict__ deg, int N) {
    int n = blockIdx.x * blockDim.x + threadIdx.x;
    if (n < N) {
        float d = deg[n] + 1.0f;
        deg[n] = (d > 0.0f) ? rsqrtf(d) : 0.0f;
    }
}
__global__ void s_kernel(const int* __restrict__ src, const int* __restrict__ dst,
                         const float* __restrict__ w, const float* __restrict__ dinv,
                         const float* __restrict__ x, float* __restrict__ s, int E) {
    int e = blockIdx.x * blockDim.x + threadIdx.x;
    if (e < E) {
        int si = src[e], di = dst[e];
        atomicAdd(&s[di], dinv[si] * w[e] * dinv[di] * x[si]);
    }
}
__global__ void g_kernel(const float* __restrict__ s, const float* __restrict__ dinv,
                         const float* __restrict__ x, const float* __restrict__ W1,
                         const float* __restrict__ b1, const float* __restrict__ W2,
                         float2* __restrict__ g, int N) {
    int n = blockIdx.x * blockDim.x + threadIdx.x;
    if (n < N) {
        float dv = dinv[n];
        float sv = s[n] + dv * dv * x[n];
        float g0 = 0.0f, g1 = 0.0f;
#pragma unroll
        for (int f = 0; f < 16; ++f) {
            float h = fmaxf(sv * W1[f] + b1[f], 0.0f);
            g0 += h * W2[2 * f + 0];
            g1 += h * W2[2 * f + 1];
        }
        g[n] = make_float2(g0, g1);
    }
}
__global__ void agg2_kernel(const int* __restrict__ src, const int* __restrict__ dst,
                            const float* __restrict__ w, const float* __restrict__ dinv,
                            const float2* __restrict__ g, float* __restrict__ agg, int E) {
    int e = blockIdx.x * blockDim.x + threadIdx.x;
    if (e < E) {
        int si = src[e], di = dst[e];
        float norm = dinv[si] * w[e] * dinv[di];
        float2 gv = g[si];
        atomicAdd(&agg[2 * di + 0], norm * gv.x);
        atomicAdd(&agg[2 * di + 1], norm * gv.y);
    }
}
__global__ void out_kernel(float* __restrict__ out, const float* __restrict__ dinv,
                           const float2* __restrict__ g, const float* __restrict__ b2, int N) {
    int n = blockIdx.x * blockDim.x + threadIdx.x;
    if (n < N) {
        float dv2 = dinv[n] * dinv[n];
        float2 gv = g[n];
        float a0 = out[2 * n + 0] + dv2 * gv.x + b2[0];
        float a1 = out[2 * n + 1] + dv2 * gv.y + b2[1];
        float m = fmaxf(a0, a1);
        float lse = m + logf(expf(a0 - m) + expf(a1 - m));
        out[2 * n + 0] = a0 - lse;
        out[2 * n + 1] = a1 - lse;
    }
}

// ======================= launch =======================

extern "C" void kernel_launch(void* const* d_in, const int* in_sizes, int n_in,
                              void* d_out, int out_size, void* d_ws, size_t ws_size,
                              hipStream_t stream) {
    const float* x  = (const float*)d_in[0];
    const int*   ei = (const int*)d_in[1];     // [2, E] delivered as int32
    const float* w  = (const float*)d_in[2];
    const float* W1 = (const float*)d_in[3];
    const float* b1 = (const float*)d_in[4];
    const float* W2 = (const float*)d_in[5];
    const float* b2 = (const float*)d_in[6];
    float* out = (float*)d_out;

    const int N = in_sizes[0];
    const int E = in_sizes[2];
    const int* src = ei;
    const int* dst = ei + E;

    const int nb   = (N + CHUNK - 1) / CHUNK;   // 782
    const int nblk = (E + EPB - 1) / EPB;       // 782

    // ws layout: payload | rowOffT (+8B uint2 pad) | dinv | xd | gd
    size_t off = 0;
    size_t payload_off = off;  off += (size_t)nblk * EPB * 8;
    size_t rowoff_off  = off;  off += (size_t)(nb + 1) * nblk * 4 + 8;
    off = (off + 7) & ~(size_t)7;
    size_t dinv_off    = off;  off += (size_t)N * 4;
    size_t xd_off      = off;  off += (size_t)N * 4;
    size_t gd_off      = off;  off += (size_t)N * 4;
    const size_t required = off;

    const bool fits = (nb <= MAXNB && nb <= 2 * BLOCK_S && nblk <= MAXBLK &&
                       nblk <= 2 * BLOCK_A && (nblk & 1) == 0 && (E % 4) == 0 &&
                       ws_size >= required);

    if (fits) {
        char* wsb = (char*)d_ws;
        unsigned long long* payload = (unsigned long long*)(wsb + payload_off);
        unsigned int* rowOffT = (unsigned int*)(wsb + rowoff_off);
        float* dinv = (float*)(wsb + dinv_off);
        float* xd   = (float*)(wsb + xd_off);
        float* gd   = (float*)(wsb + gd_off);

        scatter_kernel <<<nblk, BLOCK_S, 0, stream>>>(src, dst, w, rowOffT, payload,
                                                      E, nb, nblk);
        deg_dinv_kernel<<<nb, BLOCK_A, 0, stream>>>(payload, rowOffT, x,
                                                    dinv, xd, N, nb, nblk);
        s_gamma_kernel <<<nb, BLOCK_A, 0, stream>>>(payload, rowOffT, dinv, xd,
                                                    W1, b1, W2, gd, N, nb, nblk);
        d_out_kernel   <<<nb, BLOCK_A, 0, stream>>>(payload, rowOffT, dinv, gd, b2,
                                                    out, N, nb, nblk);
    } else {
        // R3 fallback: global-atomic path (needs 4N floats of ws)
        float*  ws   = (float*)d_ws;
        float*  dinv = ws;
        float*  s    = ws + (size_t)N;
        float2* g    = (float2*)(ws + (size_t)2 * N);
        const int gridE  = (E + BLOCK - 1) / BLOCK;
        const int gridN  = (N + BLOCK - 1) / BLOCK;
        const int gridN2 = (2 * N + BLOCK - 1) / BLOCK;
        zero_kernel<<<gridN2, BLOCK, 0, stream>>>(ws, out, 2 * N);
        deg_kernel <<<gridE,  BLOCK, 0, stream>>>(dst, w, dinv, E);
        dinv_kernel<<<gridN,  BLOCK, 0, stream>>>(dinv, N);
        s_kernel   <<<gridE,  BLOCK, 0, stream>>>(src, dst, w, dinv, x, s, E);
        g_kernel   <<<gridN,  BLOCK, 0, stream>>>(s, dinv, x, W1, b1, W2, g, N);
        agg2_kernel<<<gridE,  BLOCK, 0, stream>>>(src, dst, w, dinv, g, out, E);
        out_kernel <<<gridN,  BLOCK, 0, stream>>>(out, dinv, g, b2, N);
    }
}

// Round 7
// 182.820 us; speedup vs baseline: 1.0312x; 1.0312x over previous
//
#include <hip/hip_runtime.h>
#include <math.h>

// GCN 2-layer, N=100K, E=3.2M, feat 1->16->2, log_softmax.
//
// R5: sort tile in LDS, stream out coalesced (random 8B writes amplify 2.8x).
//     Run-offset table kills per-edge binary search. xd/gd pre-scaling.
// R6: coop monolith destroyed TLP (12 waves/CU) + ~90us coop overhead.
// R7: random global atomicAdd = memory-side RMW, ~32B HBM per 4B atomic. Never.
// R8: EPB 4096 + int4 loads fixed scatter (175 -> <42us).
// R9: agg grid-imbalance fix (CHUNK 128 / BLOCK_A 512): NEUTRAL. Aggs are not
//     occupancy-bound; they are chain-bound: table(LDS) -> payload(global,
//     782 scattered ~42B runs per bucket => ~12 random lines per wave-load)
//     -> gather -> atomic.
// R10 (resubmitted twice; R5+R6 benches were GPU-acquisition timeouts, never
//     measured): pass A becomes a REORDER pass: while computing deg via the
//     table path it also writes the bucket's edges CONTIGUOUSLY to
//     payload2[b*PAD + i] (coalesced) + bucketCnt[b]. Passes B/C then read
//     payload2 with ulonglong2 (2 edges/lane, full lines), no rowOffT scan,
//     no table, no dependent chain. PAD=5120 (+16 sigma); overflow ->
//     sentinel -> B/C fall back to the table path (uniform block branch).
//     NOTE: B/C cannot be fused into one kernel: d_out gathers gd[src] from
//     ALL buckets, so pass B must fully complete first (kernel boundary).

static constexpr int BLOCK_S   = 512;    // scatter threads
static constexpr int EPB       = 4096;   // edges per scatter tile (32 KB LDS)
static constexpr int VITERS    = EPB / (BLOCK_S * 4);  // 2 (int4 groups)
static constexpr int CHUNK     = 128;    // nodes per bucket (pow2)
static constexpr int LOG_CHUNK = 7;
static constexpr int BLOCK_A   = 512;    // aggregation threads
static constexpr int MAXNB     = 1024;   // max buckets (N <= 131072)
static constexpr int MAXBLK    = 1024;   // max scatter tiles (E <= 4.19M)
static constexpr int TABCAP    = 5120;   // run-table entries (bucket size bound)
static constexpr int PAD       = 5120;   // payload2 per-bucket capacity
static constexpr unsigned int SENT = 0xFFFFFFFFu;

// ======================= shfl-based scan =======================
// 512-thread inclusive scan: 2 barriers.
__device__ __forceinline__ unsigned int incl_scan512(unsigned int v,
                                                     unsigned int* wsum, int t) {
    unsigned int x = v;
#pragma unroll
    for (int off = 1; off < 64; off <<= 1) {
        unsigned int y = __shfl_up(x, off, 64);
        if ((t & 63) >= off) x += y;
    }
    if ((t & 63) == 63) wsum[t >> 6] = x;
    __syncthreads();
    if (t < 8) {
        unsigned int s = wsum[t];
#pragma unroll
        for (int off = 1; off < 8; off <<= 1) {
            unsigned int y = __shfl_up(s, off, 64);
            if (t >= off) s += y;
        }
        wsum[t] = s;
    }
    __syncthreads();
    return x + ((t >= 64) ? wsum[(t >> 6) - 1] : 0u);
}

__device__ __forceinline__ int run_adj_fallback(const unsigned int* cumx,
                                                const int* radj,
                                                unsigned int i, int nblk) {
    int lo = 0, hi = nblk - 1;
    while (lo < hi) {
        int mid = (lo + hi + 1) >> 1;
        if (cumx[mid] <= i) lo = mid; else hi = mid - 1;
    }
    return radj[lo];
}

// ======================= scatter: LDS sort + coalesced write-out =======================

__global__ __launch_bounds__(BLOCK_S) void scatter_kernel(
    const int* __restrict__ src, const int* __restrict__ dst,
    const float* __restrict__ w,
    unsigned int* __restrict__ rowOffT,        // [(nb+1)][nblk] transposed
    unsigned long long* __restrict__ payload,  // [nblk*EPB]
    int E, int nb, int nblk) {
    __shared__ unsigned long long pbuf[EPB];   // 32768 B staging
    __shared__ unsigned int hist[MAXNB];       // 4096 B (reused as cursor)
    __shared__ unsigned int wsum[8];
    const int blk  = blockIdx.x;
    const int base = blk * EPB;
    const int nE   = min(EPB, E - base);       // multiple of 4 (E, EPB mult 4)
    const int t    = threadIdx.x;

    hist[t]           = 0u;
    hist[t + BLOCK_S] = 0u;
    __syncthreads();

    int4 dc[VITERS];                           // static indexing -> VGPRs
#pragma unroll
    for (int i = 0; i < VITERS; ++i) {
        const int k = 4 * t + i * 4 * BLOCK_S;
        int4 d4 = make_int4(0, 0, 0, 0);
        if (k < nE) {
            d4 = *reinterpret_cast<const int4*>(&dst[base + k]);
            atomicAdd(&hist[(unsigned int)d4.x >> LOG_CHUNK], 1u);
            atomicAdd(&hist[(unsigned int)d4.y >> LOG_CHUNK], 1u);
            atomicAdd(&hist[(unsigned int)d4.z >> LOG_CHUNK], 1u);
            atomicAdd(&hist[(unsigned int)d4.w >> LOG_CHUNK], 1u);
        }
        dc[i] = d4;
    }
    __syncthreads();

    // pair-wise scan: thread t owns buckets 2t, 2t+1 (nb <= 1024)
    const unsigned int v0 = hist[2 * t], v1 = hist[2 * t + 1];
    const unsigned int pr = v0 + v1;
    const unsigned int inclp = incl_scan512(pr, wsum, t);
    const unsigned int ex0 = inclp - pr;
    const unsigned int ex1 = ex0 + v0;
    if (2 * t < nb)     rowOffT[(size_t)(2 * t) * nblk + blk]     = ex0;
    if (2 * t + 1 < nb) rowOffT[(size_t)(2 * t + 1) * nblk + blk] = ex1;
    if (t == 0)         rowOffT[(size_t)nb * nblk + blk] = (unsigned int)nE;
    hist[2 * t]     = ex0;                      // -> cursor
    hist[2 * t + 1] = ex1;
    __syncthreads();

#pragma unroll
    for (int i = 0; i < VITERS; ++i) {
        const int k = 4 * t + i * 4 * BLOCK_S;
        if (k < nE) {
            const int4   d4 = dc[i];
            const int4   s4 = *reinterpret_cast<const int4*>(&src[base + k]);
            const float4 w4 = *reinterpret_cast<const float4*>(&w[base + k]);
#define SCAT_ONE(dd, ss, ww)                                                  \
            {                                                                 \
                const unsigned int slot =                                     \
                    atomicAdd(&hist[(unsigned int)(dd) >> LOG_CHUNK], 1u);    \
                pbuf[slot] =                                                  \
                    ((unsigned long long)__float_as_uint(ww) << 32) |         \
                    ((unsigned int)(ss) << LOG_CHUNK) |                       \
                    (unsigned int)((dd) & (CHUNK - 1));                       \
            }
            SCAT_ONE(d4.x, s4.x, w4.x)
            SCAT_ONE(d4.y, s4.y, w4.y)
            SCAT_ONE(d4.z, s4.z, w4.z)
            SCAT_ONE(d4.w, s4.w, w4.w)
#undef SCAT_ONE
        }
    }
    __syncthreads();
    // coalesced, in-order global write-out, 16B per lane (nE multiple of 4)
    for (int k2 = t; k2 < (nE >> 1); k2 += BLOCK_S) {
        ulonglong2 v = *reinterpret_cast<const ulonglong2*>(&pbuf[2 * k2]);
        *reinterpret_cast<ulonglong2*>(&payload[(size_t)base + 2 * k2]) = v;
    }
}

// ======================= pass A: deg + REORDER =======================
// Table-path read (as before) computes degree AND writes the bucket's edges
// contiguously to payload2[b*PAD + i] (coalesced: i is wave-contiguous).

#define AGG_PROLOGUE                                                          \
    unsigned int s00 = 0, s01 = 0, len0 = 0, len1 = 0;                        \
    {                                                                         \
        const int e0 = 2 * t, e1 = 2 * t + 1;                                 \
        if (e0 < nblk) {                                                      \
            const uint2 r0 =                                                  \
                *reinterpret_cast<const uint2*>(&rowOffT[(size_t)b * nblk + e0]); \
            const uint2 r1 =                                                  \
                *reinterpret_cast<const uint2*>(&rowOffT[(size_t)(b + 1) * nblk + e0]); \
            s00 = r0.x; s01 = r0.y;                                           \
            len0 = r1.x - r0.x;                                               \
            len1 = (e1 < nblk) ? (r1.y - r0.y) : 0u;                          \
        }                                                                     \
        const unsigned int pr_    = len0 + len1;                              \
        const unsigned int inclp_ = incl_scan512(pr_, wsum, t);               \
        const unsigned int ex0_   = inclp_ - pr_;                             \
        const unsigned int ex1_   = ex0_ + len0;                              \
        if (e0 < nblk) { cumx[e0] = ex0_; radj[e0] = (int)s00 - (int)ex0_ + e0 * EPB; } \
        if (e1 < nblk) { cumx[e1] = ex1_; radj[e1] = (int)s01 - (int)ex1_ + e1 * EPB; } \
        if (t == ((nblk - 1) >> 1)) totsh = inclp_;                           \
        __syncthreads();                                                      \
        const unsigned int total_ = totsh;                                    \
        for (int r = e0; r <= e1 && r < nblk; ++r) {                          \
            const unsigned int beg = cumx[r];                                 \
            const unsigned int end = (r == nblk - 1) ? total_ : cumx[r + 1];  \
            const unsigned int lim = min(end, (unsigned int)TABCAP);          \
            const int a_ = radj[r];                                           \
            for (unsigned int i = beg; i < lim; ++i) table[i] = a_;           \
        }                                                                     \
    }                                                                         \
    __syncthreads();

#define TAB(i) (((i) < (unsigned int)TABCAP) ? table[i]                       \
                                             : run_adj_fallback(cumx, radj, (i), nblk))

__global__ __launch_bounds__(BLOCK_A) void deg_dinv_kernel(
    const unsigned long long* __restrict__ payload,
    unsigned long long* __restrict__ payload2,   // [nb*PAD]
    unsigned int* __restrict__ bucketCnt,        // [nb]
    const unsigned int* __restrict__ rowOffT,
    const float* __restrict__ x,
    float* __restrict__ dinv, float* __restrict__ xd,
    int N, int nb, int nblk) {
    __shared__ unsigned int cumx[MAXBLK];
    __shared__ int          radj[MAXBLK];
    __shared__ float        acc[CHUNK];
    __shared__ int          table[TABCAP];
    __shared__ unsigned int wsum[8];
    __shared__ unsigned int totsh;
    const int b = blockIdx.x, t = threadIdx.x;
    if (t < CHUNK) acc[t] = 0.0f;
    AGG_PROLOGUE
    const unsigned int total = totsh;
    const bool canw = (total <= (unsigned int)PAD);
    if (t == 0) bucketCnt[b] = canw ? total : SENT;
    unsigned long long* const p2 = payload2 + (size_t)b * PAD;
    unsigned int i = t;
    for (; i + 3u * BLOCK_A < total; i += 4u * BLOCK_A) {
        const unsigned int i0 = i, i1 = i + BLOCK_A, i2 = i + 2u * BLOCK_A,
                           i3 = i + 3u * BLOCK_A;
        const int a0 = TAB(i0), a1 = TAB(i1), a2 = TAB(i2), a3 = TAB(i3);
        const unsigned long long p0 = payload[(unsigned int)(a0 + (int)i0)];
        const unsigned long long p1 = payload[(unsigned int)(a1 + (int)i1)];
        const unsigned long long p2v = payload[(unsigned int)(a2 + (int)i2)];
        const unsigned long long p3 = payload[(unsigned int)(a3 + (int)i3)];
        if (canw) {                                   // coalesced reorder write
            p2[i0] = p0; p2[i1] = p1; p2[i2] = p2v; p2[i3] = p3;
        }
        atomicAdd(&acc[(unsigned int)p0 & (CHUNK - 1)],
                  __uint_as_float((unsigned int)(p0 >> 32)));
        atomicAdd(&acc[(unsigned int)p1 & (CHUNK - 1)],
                  __uint_as_float((unsigned int)(p1 >> 32)));
        atomicAdd(&acc[(unsigned int)p2v & (CHUNK - 1)],
                  __uint_as_float((unsigned int)(p2v >> 32)));
        atomicAdd(&acc[(unsigned int)p3 & (CHUNK - 1)],
                  __uint_as_float((unsigned int)(p3 >> 32)));
    }
    for (; i < total; i += BLOCK_A) {
        const int adj = TAB(i);
        const unsigned long long p = payload[(unsigned int)(adj + (int)i)];
        if (canw) p2[i] = p;
        atomicAdd(&acc[(unsigned int)p & (CHUNK - 1)],
                  __uint_as_float((unsigned int)(p >> 32)));
    }
    __syncthreads();
    const int n = b * CHUNK + t;
    if (t < CHUNK && n < N) {
        const float d = acc[t] + 1.0f;           // self-loop fill 1.0
        const float r = (d > 0.0f) ? rsqrtf(d) : 0.0f;
        dinv[n] = r;
        xd[n]   = r * x[n];
    }
}

// ======================= passes B/C: contiguous payload2 =======================
// Fast path: no scan, no table; ulonglong2 loads (2 edges/lane), 4-wide MLP.
// Fallback (cnt==SENT): old table path.

#define FAST_BODY(GATHER_ARR)                                                 \
    const size_t gbase = (size_t)b * PAD;                                     \
    const unsigned int npair = cnt >> 1;                                      \
    unsigned int j = t;                                                       \
    for (; j + 3u * BLOCK_A < npair; j += 4u * BLOCK_A) {                     \
        const ulonglong2 q0 = *reinterpret_cast<const ulonglong2*>(&payload2[gbase + 2u * j]); \
        const ulonglong2 q1 = *reinterpret_cast<const ulonglong2*>(&payload2[gbase + 2u * (j + BLOCK_A)]); \
        const ulonglong2 q2 = *reinterpret_cast<const ulonglong2*>(&payload2[gbase + 2u * (j + 2u * BLOCK_A)]); \
        const ulonglong2 q3 = *reinterpret_cast<const ulonglong2*>(&payload2[gbase + 2u * (j + 3u * BLOCK_A)]); \
        const float f0a = GATHER_ARR[(int)(((unsigned int)q0.x) >> LOG_CHUNK)]; \
        const float f0b = GATHER_ARR[(int)(((unsigned int)q0.y) >> LOG_CHUNK)]; \
        const float f1a = GATHER_ARR[(int)(((unsigned int)q1.x) >> LOG_CHUNK)]; \
        const float f1b = GATHER_ARR[(int)(((unsigned int)q1.y) >> LOG_CHUNK)]; \
        const float f2a = GATHER_ARR[(int)(((unsigned int)q2.x) >> LOG_CHUNK)]; \
        const float f2b = GATHER_ARR[(int)(((unsigned int)q2.y) >> LOG_CHUNK)]; \
        const float f3a = GATHER_ARR[(int)(((unsigned int)q3.x) >> LOG_CHUNK)]; \
        const float f3b = GATHER_ARR[(int)(((unsigned int)q3.y) >> LOG_CHUNK)]; \
        atomicAdd(&acc[(unsigned int)q0.x & (CHUNK - 1)], __uint_as_float((unsigned int)(q0.x >> 32)) * f0a); \
        atomicAdd(&acc[(unsigned int)q0.y & (CHUNK - 1)], __uint_as_float((unsigned int)(q0.y >> 32)) * f0b); \
        atomicAdd(&acc[(unsigned int)q1.x & (CHUNK - 1)], __uint_as_float((unsigned int)(q1.x >> 32)) * f1a); \
        atomicAdd(&acc[(unsigned int)q1.y & (CHUNK - 1)], __uint_as_float((unsigned int)(q1.y >> 32)) * f1b); \
        atomicAdd(&acc[(unsigned int)q2.x & (CHUNK - 1)], __uint_as_float((unsigned int)(q2.x >> 32)) * f2a); \
        atomicAdd(&acc[(unsigned int)q2.y & (CHUNK - 1)], __uint_as_float((unsigned int)(q2.y >> 32)) * f2b); \
        atomicAdd(&acc[(unsigned int)q3.x & (CHUNK - 1)], __uint_as_float((unsigned int)(q3.x >> 32)) * f3a); \
        atomicAdd(&acc[(unsigned int)q3.y & (CHUNK - 1)], __uint_as_float((unsigned int)(q3.y >> 32)) * f3b); \
    }                                                                         \
    for (; j < npair; j += BLOCK_A) {                                         \
        const ulonglong2 q = *reinterpret_cast<const ulonglong2*>(&payload2[gbase + 2u * j]); \
        const float fa = GATHER_ARR[(int)(((unsigned int)q.x) >> LOG_CHUNK)]; \
        const float fb = GATHER_ARR[(int)(((unsigned int)q.y) >> LOG_CHUNK)]; \
        atomicAdd(&acc[(unsigned int)q.x & (CHUNK - 1)], __uint_as_float((unsigned int)(q.x >> 32)) * fa); \
        atomicAdd(&acc[(unsigned int)q.y & (CHUNK - 1)], __uint_as_float((unsigned int)(q.y >> 32)) * fb); \
    }                                                                         \
    if ((cnt & 1u) && t == 0) {                                               \
        const unsigned long long q = payload2[gbase + cnt - 1u];              \
        atomicAdd(&acc[(unsigned int)q & (CHUNK - 1)],                        \
                  __uint_as_float((unsigned int)(q >> 32)) *                  \
                      GATHER_ARR[(int)(((unsigned int)q) >> LOG_CHUNK)]);     \
    }

#define FB_BODY(GATHER_ARR)                                                   \
    AGG_PROLOGUE                                                              \
    const unsigned int total = totsh;                                         \
    for (unsigned int i = t; i < total; i += BLOCK_A) {                       \
        const int adj = TAB(i);                                               \
        const unsigned long long p = payload[(unsigned int)(adj + (int)i)];   \
        atomicAdd(&acc[(unsigned int)p & (CHUNK - 1)],                        \
                  __uint_as_float((unsigned int)(p >> 32)) *                  \
                      GATHER_ARR[(int)(((unsigned int)p) >> LOG_CHUNK)]);     \
    }

__global__ __launch_bounds__(BLOCK_A) void s_gamma_kernel(
    const unsigned long long* __restrict__ payload,
    const unsigned long long* __restrict__ payload2,
    const unsigned int* __restrict__ bucketCnt,
    const unsigned int* __restrict__ rowOffT,
    const float* __restrict__ dinv,
    const float* __restrict__ xd,
    const float* __restrict__ W1,    // [16]
    const float* __restrict__ b1,    // [16]
    const float* __restrict__ W2,    // [16][2]
    float* __restrict__ gd, int N, int nb, int nblk) {
    __shared__ unsigned int cumx[MAXBLK];
    __shared__ int          radj[MAXBLK];
    __shared__ float        acc[CHUNK];
    __shared__ int          table[TABCAP];
    __shared__ unsigned int wsum[8];
    __shared__ unsigned int totsh;
    const int b = blockIdx.x, t = threadIdx.x;
    const unsigned int cnt = bucketCnt[b];
    if (t < CHUNK) acc[t] = 0.0f;
    __syncthreads();
    if (cnt != SENT) {          // uniform per-block branch
        FAST_BODY(xd)
    } else {
        FB_BODY(xd)
    }
    __syncthreads();
    const int n = b * CHUNK + t;
    if (t < CHUNK && n < N) {
        const float dv = dinv[n];
        const float sv = dv * (acc[t] + xd[n]);   // + self-loop dv*dv*x[n]
        float g = 0.0f;
#pragma unroll
        for (int f = 0; f < 16; ++f) {
            const float h = fmaxf(sv * W1[f] + b1[f], 0.0f);   // relu(layer1)
            g += h * (W2[2 * f + 1] - W2[2 * f + 0]);          // gamma = g1-g0
        }
        gd[n] = dv * g;                           // pre-scaled for layer 2
    }
}

__global__ __launch_bounds__(BLOCK_A) void d_out_kernel(
    const unsigned long long* __restrict__ payload,
    const unsigned long long* __restrict__ payload2,
    const unsigned int* __restrict__ bucketCnt,
    const unsigned int* __restrict__ rowOffT,
    const float* __restrict__ dinv,
    const float* __restrict__ gd,
    const float* __restrict__ b2,    // [2]
    float* __restrict__ out, int N, int nb, int nblk) {
    __shared__ unsigned int cumx[MAXBLK];
    __shared__ int          radj[MAXBLK];
    __shared__ float        acc[CHUNK];
    __shared__ int          table[TABCAP];
    __shared__ unsigned int wsum[8];
    __shared__ unsigned int totsh;
    const int b = blockIdx.x, t = threadIdx.x;
    const unsigned int cnt = bucketCnt[b];
    if (t < CHUNK) acc[t] = 0.0f;
    __syncthreads();
    if (cnt != SENT) {
        FAST_BODY(gd)
    } else {
        FB_BODY(gd)
    }
    __syncthreads();
    const int n = b * CHUNK + t;
    if (t < CHUNK && n < N) {
        const float dv = dinv[n];
        const float d = dv * (acc[t] + gd[n]) + (b2[1] - b2[0]);
        // 2-class log_softmax from d = a1 - a0 (stable)
        const float lse = fmaxf(d, 0.0f) + log1pf(expf(-fabsf(d)));
        out[2 * n + 0] = -lse;
        out[2 * n + 1] = d - lse;
    }
}

// ======================= fallback: R3 global-atomic path =======================

static constexpr int BLOCK = 256;

__global__ void zero_kernel(float* __restrict__ a, float* __restrict__ b, int n2) {
    int i = blockIdx.x * blockDim.x + threadIdx.x;
    if (i < n2) { a[i] = 0.0f; b[i] = 0.0f; }
}
__global__ void deg_kernel(const int* __restrict__ dst, const float* __restrict__ w,
                           float* __restrict__ deg, int E) {
    int e = blockIdx.x * blockDim.x + threadIdx.x;
    if (e < E) atomicAdd(&deg[dst[e]], w[e]);
}
__global__ void dinv_kernel(float* __restrict__ deg, int N) {
    int n = blockIdx.x * blockDim.x + threadIdx.x;
    if (n < N) {
        float d = deg[n] + 1.0f;
        deg[n] = (d > 0.0f) ? rsqrtf(d) : 0.0f;
    }
}
__global__ void s_kernel(const int* __restrict__ src, const int* __restrict__ dst,
                         const float* __restrict__ w, const float* __restrict__ dinv,
                         const float* __restrict__ x, float* __restrict__ s, int E) {
    int e = blockIdx.x * blockDim.x + threadIdx.x;
    if (e < E) {
        int si = src[e], di = dst[e];
        atomicAdd(&s[di], dinv[si] * w[e] * dinv[di] * x[si]);
    }
}
__global__ void g_kernel(const float* __restrict__ s, const float* __restrict__ dinv,
                         const float* __restrict__ x, const float* __restrict__ W1,
                         const float* __restrict__ b1, const float* __restrict__ W2,
                         float2* __restrict__ g, int N) {
    int n = blockIdx.x * blockDim.x + threadIdx.x;
    if (n < N) {
        float dv = dinv[n];
        float sv = s[n] + dv * dv * x[n];
        float g0 = 0.0f, g1 = 0.0f;
#pragma unroll
        for (int f = 0; f < 16; ++f) {
            float h = fmaxf(sv * W1[f] + b1[f], 0.0f);
            g0 += h * W2[2 * f + 0];
            g1 += h * W2[2 * f + 1];
        }
        g[n] = make_float2(g0, g1);
    }
}
__global__ void agg2_kernel(const int* __restrict__ src, const int* __restrict__ dst,
                            const float* __restrict__ w, const float* __restrict__ dinv,
                            const float2* __restrict__ g, float* __restrict__ agg, int E) {
    int e = blockIdx.x * blockDim.x + threadIdx.x;
    if (e < E) {
        int si = src[e], di = dst[e];
        float norm = dinv[si] * w[e] * dinv[di];
        float2 gv = g[si];
        atomicAdd(&agg[2 * di + 0], norm * gv.x);
        atomicAdd(&agg[2 * di + 1], norm * gv.y);
    }
}
__global__ void out_kernel(float* __restrict__ out, const float* __restrict__ dinv,
                           const float2* __restrict__ g, const float* __restrict__ b2, int N) {
    int n = blockIdx.x * blockDim.x + threadIdx.x;
    if (n < N) {
        float dv2 = dinv[n] * dinv[n];
        float2 gv = g[n];
        float a0 = out[2 * n + 0] + dv2 * gv.x + b2[0];
        float a1 = out[2 * n + 1] + dv2 * gv.y + b2[1];
        float m = fmaxf(a0, a1);
        float lse = m + logf(expf(a0 - m) + expf(a1 - m));
        out[2 * n + 0] = a0 - lse;
        out[2 * n + 1] = a1 - lse;
    }
}

// ======================= launch =======================

extern "C" void kernel_launch(void* const* d_in, const int* in_sizes, int n_in,
                              void* d_out, int out_size, void* d_ws, size_t ws_size,
                              hipStream_t stream) {
    const float* x  = (const float*)d_in[0];
    const int*   ei = (const int*)d_in[1];     // [2, E] delivered as int32
    const float* w  = (const float*)d_in[2];
    const float* W1 = (const float*)d_in[3];
    const float* b1 = (const float*)d_in[4];
    const float* W2 = (const float*)d_in[5];
    const float* b2 = (const float*)d_in[6];
    float* out = (float*)d_out;

    const int N = in_sizes[0];
    const int E = in_sizes[2];
    const int* src = ei;
    const int* dst = ei + E;

    const int nb   = (N + CHUNK - 1) / CHUNK;   // 782
    const int nblk = (E + EPB - 1) / EPB;       // 782

    // ws layout: payload | payload2 | rowOffT (+pad) | bucketCnt | dinv | xd | gd
    size_t off = 0;
    size_t payload_off  = off;  off += (size_t)nblk * EPB * 8;
    size_t payload2_off = off;  off += (size_t)nb * PAD * 8;
    size_t rowoff_off   = off;  off += (size_t)(nb + 1) * nblk * 4 + 8;
    off = (off + 7) & ~(size_t)7;
    size_t bcnt_off     = off;  off += (size_t)nb * 4;
    size_t dinv_off     = off;  off += (size_t)N * 4;
    size_t xd_off       = off;  off += (size_t)N * 4;
    size_t gd_off       = off;  off += (size_t)N * 4;
    const size_t required = off;

    const bool fits = (nb <= MAXNB && nb <= 2 * BLOCK_S && nblk <= MAXBLK &&
                       nblk <= 2 * BLOCK_A && (nblk & 1) == 0 && (E % 4) == 0 &&
                       ws_size >= required);

    if (fits) {
        char* wsb = (char*)d_ws;
        unsigned long long* payload  = (unsigned long long*)(wsb + payload_off);
        unsigned long long* payload2 = (unsigned long long*)(wsb + payload2_off);
        unsigned int* rowOffT   = (unsigned int*)(wsb + rowoff_off);
        unsigned int* bucketCnt = (unsigned int*)(wsb + bcnt_off);
        float* dinv = (float*)(wsb + dinv_off);
        float* xd   = (float*)(wsb + xd_off);
        float* gd   = (float*)(wsb + gd_off);

        scatter_kernel <<<nblk, BLOCK_S, 0, stream>>>(src, dst, w, rowOffT, payload,
                                                      E, nb, nblk);
        deg_dinv_kernel<<<nb, BLOCK_A, 0, stream>>>(payload, payload2, bucketCnt,
                                                    rowOffT, x, dinv, xd, N, nb, nblk);
        s_gamma_kernel <<<nb, BLOCK_A, 0, stream>>>(payload, payload2, bucketCnt,
                                                    rowOffT, dinv, xd,
                                                    W1, b1, W2, gd, N, nb, nblk);
        d_out_kernel   <<<nb, BLOCK_A, 0, stream>>>(payload, payload2, bucketCnt,
                                                    rowOffT, dinv, gd, b2,
                                                    out, N, nb, nblk);
    } else {
        // R3 fallback: global-atomic path (needs 4N floats of ws)
        float*  ws   = (float*)d_ws;
        float*  dinv = ws;
        float*  s    = ws + (size_t)N;
        float2* g    = (float2*)(ws + (size_t)2 * N);
        const int gridE  = (E + BLOCK - 1) / BLOCK;
        const int gridN  = (N + BLOCK - 1) / BLOCK;
        const int gridN2 = (2 * N + BLOCK - 1) / BLOCK;
        zero_kernel<<<gridN2, BLOCK, 0, stream>>>(ws, out, 2 * N);
        deg_kernel <<<gridE,  BLOCK, 0, stream>>>(dst, w, dinv, E);
        dinv_kernel<<<gridN,  BLOCK, 0, stream>>>(dinv, N);
        s_kernel   <<<gridE,  BLOCK, 0, stream>>>(src, dst, w, dinv, x, s, E);
        g_kernel   <<<gridN,  BLOCK, 0, stream>>>(s, dinv, x, W1, b1, W2, g, N);
        agg2_kernel<<<gridE,  BLOCK, 0, stream>>>(src, dst, w, dinv, g, out, E);
        out_kernel <<<gridN,  BLOCK, 0, stream>>>(out, dinv, g, b2, N);
    }
}